// Round 11
// baseline (131.962 us; speedup 1.0000x reference)
//
#include <hip/hip_runtime.h>
#include <hip/hip_fp16.h>

#define N_ANG 256
#define N_BATCH 8
#define STRIDE 261                  // dword row stride (259 used + 2 pad); 261%32=5
#define MAXROWS 67                  // nE+2 <= 67

#if defined(__has_builtin)
#  if __has_builtin(__builtin_amdgcn_fdot2) && __has_builtin(__builtin_amdgcn_cvt_pkrtz)
#    define HAVE_FDOT2 1
#  endif
#  if __has_builtin(__builtin_amdgcn_fractf)
#    define FRACT(x) __builtin_amdgcn_fractf(x)
#  endif
#endif
#ifndef FRACT
#  define FRACT(x) ((x) - floorf(x))
#endif

typedef __fp16 fp16x2 __attribute__((ext_vector_type(2)));
typedef _Float16 h2 __attribute__((ext_vector_type(2)));

// R9 structure (adaptive band axis, quarter bands, overlapping-pair texture,
// fdot2 vertical lerp, 2 blocks/CU) + issue diet:
//  - +2-shifted coords (always > 0) -> v_fract weight + truncating cvt = floor
//  - sf-driven loop (no int si counter)
//  - swapped staging: compile-time div-by-68 (magic mul) instead of runtime TT
__global__ __launch_bounds__(1024, 8) void radon_f(const float* __restrict__ x,
                                                   const float* __restrict__ angles,
                                                   float* __restrict__ out) {
    __shared__ uint32_t S[MAXROWS * STRIDE];   // 17,487 dw = 69,948 B

    int bid  = blockIdx.x;
    int b    = bid & 7;              // batch (XCD-resident image)
    int rest = bid >> 3;
    int agrp = rest & 63;            // 4 angles per block
    int qq   = rest >> 6;            // quarter 0..3
    int prLo = (qq == 0) ? 0 : (qq * 64 + 1);
    int nE   = (qq == 0) ? 65 : 64;
    int tid  = threadIdx.x;

    // group-uniform axis choice (same for all 4 quarter-blocks of this agrp)
    float angRep = 0.5f * (angles[agrp * 4 + 1] + angles[agrp * 4 + 2]);
    bool swapped = fabsf(sinf(angRep)) > fabsf(cosf(angRep));

    const float* im = x + (size_t)b * 65536;
    int TT = nE + 2;
    if (!swapped) {
        // row bands: flat idx, compile-time magic div by 261; coalesced reads
        int nEnt = TT * STRIDE;
        for (int idx = tid; idx < nEnt; idx += 1024) {
            int t = (int)((unsigned)idx / (unsigned)STRIDE);
            int u = idx - t * STRIDE;
            int c = u - 2;
            int rT = prLo + t - 2, rB = rT + 1;
            bool real = (t >= 1) & (t <= nE) & ((unsigned)c < 256u);
            float vT = (real && (unsigned)rT < 256u) ? im[rT * 256 + c] : 0.0f;
            float vB = (real && (unsigned)rB < 256u) ? im[rB * 256 + c] : 0.0f;
            __half2 hv = __floats2half2_rn(vT, vB);
            S[idx] = *reinterpret_cast<const uint32_t*>(&hv);
        }
    } else {
        // col bands: E[r'][c'] = img[c'][r']; t fastest -> coalesced global,
        // LDS write stride 261 dw = 5 mod 32 banks -> conflict-free.
        // Compile-time div by 68 (t in [0,68), ghost rows t>=TT guarded out).
        for (int e = tid; e < 68 * STRIDE; e += 1024) {
            int u = (int)((unsigned)e / 68u);
            int t = e - u * 68;
            if (t < TT) {
                int c = u - 2;                        // image row
                int rT = prLo + t - 2, rB = rT + 1;   // image cols
                bool real = (t >= 1) & (t <= nE) & ((unsigned)c < 256u);
                float vT = (real && (unsigned)rT < 256u) ? im[c * 256 + rT] : 0.0f;
                float vB = (real && (unsigned)rB < 256u) ? im[c * 256 + rB] : 0.0f;
                __half2 hv = __floats2half2_rn(vT, vB);
                S[t * STRIDE + u] = *reinterpret_cast<const uint32_t*>(&hv);
            }
        }
    }
    __syncthreads();

    // ---- ray setup (padded coords = ref+1, then +2 shift for positivity)
    int d = tid & 255;
    int a = agrp * 4 + (tid >> 8);
    float ang = angles[a];
    float sn = sinf(ang), cs = cosf(ang);
    float td = (float)d - 127.5f;
    float Xb = fmaf(td, cs, 130.5f);   // 128.5 + 2
    float Yb = fmaf(td, sn, 130.5f);
    // band coords: R = band axis (|dR| >= 0.707), C = cross axis
    float Rb, dR, Cb, dC;
    if (!swapped) { Rb = Yb; dR = cs;  Cb = Xb; dC = -sn; }
    else          { Rb = Xb; dR = -sn; Cb = Yb; dC = cs;  }

    // per-lane sf window, 0.25-margin crossings via v_rcp.
    // Shifted valid ranges: Rp2 in [prLo+2, prLo+nE+2), Cp2 in [2, 259).
    float lo = -127.5f, hi = 127.5f;
    {
        float r = __builtin_amdgcn_rcpf(dR);
        float p  = ((float)(prLo + 2) - 0.25f - Rb) * r;
        float q2 = ((float)(prLo + nE + 2) + 0.25f - Rb) * r;
        lo = fmaxf(lo, fminf(p, q2)); hi = fminf(hi, fmaxf(p, q2));
    }
    {
        float r = __builtin_amdgcn_rcpf(dC);
        float p  = (1.75f - Cb) * r;
        float q2 = (259.25f - Cb) * r;
        lo = fmaxf(lo, fminf(p, q2)); hi = fminf(hi, fmaxf(p, q2));
    }
    int siLo = max(0,   (int)ceilf(lo + 127.5f));
    int siHi = min(255, (int)floorf(hi + 127.5f));

    // byte idx = ifr2*1044 + ifc2*4 + KOFFB2, folding the -2 shifts and the
    // texture's (t = pr-prLo+1, u = cp+1) mapping.
    int KOFFB2 = ((1 - prLo) * STRIDE + 1) * 4 - 2 * (STRIDE * 4) - 8;

    // ---- main loop: 1 ds_read2_b32 + ~17 VALU per sample
    float accB = 0.0f, accD = 0.0f;
    float sf   = (float)siLo - 127.5f;
    float sfHi = (float)siHi - 127.5f;
    #pragma unroll 4
    for (; sf <= sfHi; sf += 1.0f) {
        float Rp = fmaf(sf, dR, Rb);
        float Cp = fmaf(sf, dC, Cb);
        float wr = FRACT(Rp);
        float wc = FRACT(Cp);
        int ifr = (int)Rp;           // trunc == floor (Rp > 0)
        int ifc = (int)Cp;
        int baddr = ifr * (STRIDE * 4) + (ifc << 2) + KOFFB2;
        uint32_t A0 = *(const uint32_t*)((const char*)S + baddr);
        uint32_t A1 = *(const uint32_t*)((const char*)S + baddr + 4);  // ds_read2
#ifdef HAVE_FDOT2
        fp16x2 wnv = __builtin_amdgcn_cvt_pkrtz(1.0f - wr, wr);        // (1-wr, wr)
        h2 wn = *reinterpret_cast<h2*>(&wnv);
        float rL = __builtin_amdgcn_fdot2(*(h2*)&A0, wn, 0.0f, false); // vert lerp L
        float rR = __builtin_amdgcn_fdot2(*(h2*)&A1, wn, 0.0f, false); // vert lerp R
        accB += rL;
        accD = fmaf(wc, rR - rL, accD);                                // horiz lerp
#else
        __half2 Ah = *reinterpret_cast<__half2*>(&A0);
        __half2 Bh = *reinterpret_cast<__half2*>(&A1);
        float tL = __low2float(Ah), bL = __high2float(Ah);
        float tR = __low2float(Bh), bR = __high2float(Bh);
        float rL = fmaf(wr, bL - tL, tL);
        float rR = fmaf(wr, bR - tR, tR);
        accB += rL;
        accD = fmaf(wc, rR - rL, accD);
#endif
    }
    if (siLo <= siHi)
        unsafeAtomicAdd(&out[((size_t)b * N_ANG + a) * 256 + d], accB + accD);
}

extern "C" void kernel_launch(void* const* d_in, const int* in_sizes, int n_in,
                              void* d_out, int out_size, void* d_ws, size_t ws_size,
                              hipStream_t stream) {
    const float* x      = (const float*)d_in[0];
    const float* angles = (const float*)d_in[1];
    float* out = (float*)d_out;
    (void)hipMemsetAsync(out, 0, (size_t)out_size * sizeof(float), stream);
    // 2048 blocks = 8 batches x 64 angle-groups x 4 quarters; batch = blockIdx%8
    radon_f<<<N_BATCH * (N_ANG / 4) * 4, 1024, 0, stream>>>(x, angles, out);
}

// Round 12
// 118.172 us; speedup vs baseline: 1.1167x; 1.1167x over previous
//
#include <hip/hip_runtime.h>
#include <hip/hip_fp16.h>

#define N_ANG 256
#define N_BATCH 8
#define STRIDE 261                  // dword row stride (259 used + 2 pad)
#define MAXROWS 67                  // nE+2 <= 67

#if defined(__has_builtin)
#  if __has_builtin(__builtin_amdgcn_fdot2) && __has_builtin(__builtin_amdgcn_cvt_pkrtz)
#    define HAVE_FDOT2 1
#  endif
#endif

typedef __fp16 fp16x2 __attribute__((ext_vector_type(2)));   // builtin's native type
typedef _Float16 h2 __attribute__((ext_vector_type(2)));

// Best-known configuration (R9, 118 us): adaptive band axis, quarter bands,
// overlapping-pair fp16 texture, fdot2 vertical lerp, 2 blocks/CU.
// R10's further instruction diet REGRESSED (issue efficiency loss) — this is
// the empirical VALU-issue floor for this decomposition.
__global__ __launch_bounds__(1024, 8) void radon_d(const float* __restrict__ x,
                                                   const float* __restrict__ angles,
                                                   float* __restrict__ out) {
    __shared__ uint32_t S[MAXROWS * STRIDE];   // 17,487 dw = 69,948 B

    int bid  = blockIdx.x;
    int b    = bid & 7;              // batch (XCD-resident image)
    int rest = bid >> 3;
    int agrp = rest & 63;            // 4 angles per block
    int qq   = rest >> 6;            // quarter 0..3
    int prLo = (qq == 0) ? 0 : (qq * 64 + 1);
    int nE   = (qq == 0) ? 65 : 64;
    int tid  = threadIdx.x;

    // group-uniform axis choice (same for all 4 quarter-blocks of this agrp)
    float angRep = 0.5f * (angles[agrp * 4 + 1] + angles[agrp * 4 + 2]);
    bool swapped = fabsf(sinf(angRep)) > fabsf(cosf(angRep));

    const float* im = x + (size_t)b * 65536;
    int TT = nE + 2;
    int nEnt = TT * STRIDE;
    if (!swapped) {
        // row bands: consecutive threads -> consecutive u -> coalesced reads
        for (int idx = tid; idx < nEnt; idx += 1024) {
            int t = idx / STRIDE;
            int u = idx - t * STRIDE;
            int c = u - 2;
            int rT = prLo + t - 2, rB = rT + 1;
            bool real = (t >= 1) & (t <= nE) & ((unsigned)c < 256u);
            float vT = (real && (unsigned)rT < 256u) ? im[rT * 256 + c] : 0.0f;
            float vB = (real && (unsigned)rB < 256u) ? im[rB * 256 + c] : 0.0f;
            __half2 hv = __floats2half2_rn(vT, vB);
            S[idx] = *reinterpret_cast<const uint32_t*>(&hv);
        }
    } else {
        // col bands: E[r'][c'] = img[c'][r']; t fastest -> coalesced global,
        // LDS write stride 261 dw = 5 mod 32 banks -> conflict-free.
        for (int e = tid; e < nEnt; e += 1024) {
            int u = e / TT;
            int t = e - u * TT;
            int c = u - 2;                        // image row
            int rT = prLo + t - 2, rB = rT + 1;   // image cols
            bool real = (t >= 1) & (t <= nE) & ((unsigned)c < 256u);
            float vT = (real && (unsigned)rT < 256u) ? im[c * 256 + rT] : 0.0f;
            float vB = (real && (unsigned)rB < 256u) ? im[c * 256 + rB] : 0.0f;
            __half2 hv = __floats2half2_rn(vT, vB);
            S[t * STRIDE + u] = *reinterpret_cast<const uint32_t*>(&hv);
        }
    }
    __syncthreads();

    // ---- ray setup (padded coords = ref+1): Xp = Xb - sf*sn, Yp = Yb + sf*cs
    int d = tid & 255;
    int a = agrp * 4 + (tid >> 8);
    float ang = angles[a];
    float sn = sinf(ang), cs = cosf(ang);
    float td = (float)d - 127.5f;
    float Xb = fmaf(td, cs, 128.5f);
    float Yb = fmaf(td, sn, 128.5f);
    // band coords: R = band axis (|dR| >= 0.707), C = cross axis
    float Rb, dR, Cb, dC;
    if (!swapped) { Rb = Yb; dR = cs;  Cb = Xb; dC = -sn; }
    else          { Rb = Xb; dR = -sn; Cb = Yb; dC = cs;  }

    // per-lane sf window, 0.25-margin crossings via v_rcp (guards absorb slop).
    float lo = -127.5f, hi = 127.5f;
    {
        float r = __builtin_amdgcn_rcpf(dR);
        float p = ((float)prLo - 0.25f - Rb) * r;
        float q2 = ((float)(prLo + nE) + 0.25f - Rb) * r;
        lo = fmaxf(lo, fminf(p, q2)); hi = fminf(hi, fmaxf(p, q2));
    }
    {
        float r = __builtin_amdgcn_rcpf(dC);
        float p = (-0.25f - Cb) * r;
        float q2 = (257.25f - Cb) * r;
        lo = fmaxf(lo, fminf(p, q2)); hi = fminf(hi, fmaxf(p, q2));
    }
    int siLo = max(0,   (int)ceilf(lo + 127.5f));
    int siHi = min(255, (int)floorf(hi + 127.5f));

    int KOFFB = ((1 - prLo) * STRIDE + 1) * 4;   // byte offset fold

    // ---- main loop: 1 ds_read2_b32 + ~17 VALU per sample
    float accB = 0.0f, accD = 0.0f;
    float sf = (float)siLo - 127.5f;
    #pragma unroll 4
    for (int si = siLo; si <= siHi; ++si) {
        float Rp = fmaf(sf, dR, Rb);
        float Cp = fmaf(sf, dC, Cb);
        sf += 1.0f;
        float fr = floorf(Rp), fc = floorf(Cp);
        float wr = Rp - fr, wc = Cp - fc;
        int baddr = (int)fr * (STRIDE * 4) + (int)fc * 4 + KOFFB;
        uint32_t A0 = *(const uint32_t*)((const char*)S + baddr);
        uint32_t A1 = *(const uint32_t*)((const char*)S + baddr + 4);  // ds_read2
#ifdef HAVE_FDOT2
        fp16x2 wnv = __builtin_amdgcn_cvt_pkrtz(1.0f - wr, wr);        // (1-wr, wr)
        h2 wn = *reinterpret_cast<h2*>(&wnv);
        float rL = __builtin_amdgcn_fdot2(*(h2*)&A0, wn, 0.0f, false); // vert lerp L
        float rR = __builtin_amdgcn_fdot2(*(h2*)&A1, wn, 0.0f, false); // vert lerp R
        accB += rL;
        accD = fmaf(wc, rR - rL, accD);                                // horiz lerp
#else
        __half2 Ah = *reinterpret_cast<__half2*>(&A0);
        __half2 Bh = *reinterpret_cast<__half2*>(&A1);
        float tL = __low2float(Ah), bL = __high2float(Ah);
        float tR = __low2float(Bh), bR = __high2float(Bh);
        float rL = fmaf(wr, bL - tL, tL);
        float rR = fmaf(wr, bR - tR, tR);
        accB += rL;
        accD = fmaf(wc, rR - rL, accD);
#endif
    }
    if (siLo <= siHi)
        unsafeAtomicAdd(&out[((size_t)b * N_ANG + a) * 256 + d], accB + accD);
}

extern "C" void kernel_launch(void* const* d_in, const int* in_sizes, int n_in,
                              void* d_out, int out_size, void* d_ws, size_t ws_size,
                              hipStream_t stream) {
    const float* x      = (const float*)d_in[0];
    const float* angles = (const float*)d_in[1];
    float* out = (float*)d_out;
    (void)hipMemsetAsync(out, 0, (size_t)out_size * sizeof(float), stream);
    // 2048 blocks = 8 batches x 64 angle-groups x 4 quarters; batch = blockIdx%8
    radon_d<<<N_BATCH * (N_ANG / 4) * 4, 1024, 0, stream>>>(x, angles, out);
}